// Round 1
// baseline (612.666 us; speedup 1.0000x reference)
//
#include <hip/hip_runtime.h>
#include <hip/hip_bf16.h>

// GCN node encoder: 3 layers of GraphConv(norm=both) + residual linear + ReLU + BatchNorm
// N=50000, E=500000, D=128, L=3. All fp32 baseline (round 1).

#define TPB 256

// ---------------- setup kernels ----------------

__global__ void init_zero(int* __restrict__ ints, int ni, float* __restrict__ fs, int nf) {
    int i = blockIdx.x * blockDim.x + threadIdx.x;
    int stride = gridDim.x * blockDim.x;
    for (int k = i; k < ni; k += stride) ints[k] = 0;
    for (int k = i; k < nf; k += stride) fs[k] = 0.f;
}

__global__ void degree_kernel(const int* __restrict__ src, const int* __restrict__ dst,
                              int* __restrict__ deg_src, int* __restrict__ deg_dst, int e) {
    int i = blockIdx.x * blockDim.x + threadIdx.x;
    if (i < e) {
        atomicAdd(&deg_src[src[i]], 1);
        atomicAdd(&deg_dst[dst[i]], 1);
    }
}

__global__ void norm_kernel(const int* __restrict__ deg_src, const int* __restrict__ deg_dst,
                            float* __restrict__ out_norm, float* __restrict__ in_norm, int n) {
    int v = blockIdx.x * blockDim.x + threadIdx.x;
    if (v < n) {
        int ds = deg_src[v];
        int dd = deg_dst[v];
        out_norm[v] = ds > 0 ? 1.0f / sqrtf((float)ds) : 0.0f;
        in_norm[v]  = dd > 0 ? 1.0f / sqrtf((float)dd) : 0.0f;
    }
}

// block-wise exclusive scan of deg_dst (1024 per block)
__global__ void scan1(const int* __restrict__ deg, int* __restrict__ excl,
                      int* __restrict__ bsum, int n) {
    __shared__ int tmp[1024];
    int t = threadIdx.x;
    int i = blockIdx.x * 1024 + t;
    int v = (i < n) ? deg[i] : 0;
    tmp[t] = v;
    __syncthreads();
    for (int off = 1; off < 1024; off <<= 1) {
        int add = (t >= off) ? tmp[t - off] : 0;
        __syncthreads();
        tmp[t] += add;
        __syncthreads();
    }
    if (i < n) excl[i] = tmp[t] - v;
    if (t == 1023) bsum[blockIdx.x] = tmp[1023];
}

__global__ void scan2(const int* __restrict__ bsum, int* __restrict__ boff, int nb) {
    if (threadIdx.x == 0 && blockIdx.x == 0) {
        int run = 0;
        for (int i = 0; i < nb; i++) { boff[i] = run; run += bsum[i]; }
    }
}

__global__ void scan3(const int* __restrict__ excl, const int* __restrict__ boff,
                      int* __restrict__ row_ptr, int n, int e) {
    int i = blockIdx.x * blockDim.x + threadIdx.x;
    if (i < n) row_ptr[i] = excl[i] + boff[i >> 10];
    if (i == n) row_ptr[n] = e;
}

__global__ void scatter_kernel(const int* __restrict__ src, const int* __restrict__ dst,
                               const int* __restrict__ row_ptr, int* __restrict__ cursor,
                               int* __restrict__ col_idx, int e) {
    int i = blockIdx.x * blockDim.x + threadIdx.x;
    if (i < e) {
        int d = dst[i];
        int pos = row_ptr[d] + atomicAdd(&cursor[d], 1);
        col_idx[pos] = src[i];
    }
}

__global__ void embed_kernel(const int* __restrict__ node_ids, const float* __restrict__ emb,
                             float* __restrict__ x, int n) {
    int gid = blockIdx.x * blockDim.x + threadIdx.x;
    if (gid >= n * 32) return;
    int v = gid >> 5, c4 = gid & 31;
    int id = node_ids[v];
    float4 e = *(const float4*)&emb[id * 128 + c4 * 4];
    *(float4*)&x[(size_t)v * 128 + c4 * 4] = e;
}

// ---------------- per-layer kernels ----------------

// one wave (64 lanes) per destination node; lane holds 2 feature columns
__global__ void agg_kernel(const float* __restrict__ x, const int* __restrict__ row_ptr,
                           const int* __restrict__ col_idx, const float* __restrict__ out_norm,
                           const float* __restrict__ in_norm, float* __restrict__ agg, int n) {
    int gtid = blockIdx.x * blockDim.x + threadIdx.x;
    int node = gtid >> 6;
    int lane = threadIdx.x & 63;
    if (node >= n) return;
    int beg = row_ptr[node], end = row_ptr[node + 1];
    const float2* xf2 = (const float2*)x;
    float2 acc = {0.f, 0.f};
    int i = beg;
    for (; i + 1 < end; i += 2) {
        int u0 = col_idx[i], u1 = col_idx[i + 1];
        float n0 = out_norm[u0], n1 = out_norm[u1];
        float2 v0 = xf2[(size_t)u0 * 64 + lane];
        float2 v1 = xf2[(size_t)u1 * 64 + lane];
        acc.x += n0 * v0.x + n1 * v1.x;
        acc.y += n0 * v0.y + n1 * v1.y;
    }
    if (i < end) {
        int u = col_idx[i];
        float nn = out_norm[u];
        float2 v = xf2[(size_t)u * 64 + lane];
        acc.x += nn * v.x;
        acc.y += nn * v.y;
    }
    float inv = in_norm[node];
    acc.x *= inv; acc.y *= inv;
    ((float2*)agg)[(size_t)node * 64 + lane] = acc;
}

// h = relu(agg@W + b) + relu(x@Rw + Rb); accumulate BN sums/sumsq into 64-bank stats
#define BM 32
__global__ __launch_bounds__(256) void gemm_kernel(
    const float* __restrict__ agg, const float* __restrict__ x,
    const float* __restrict__ W, const float* __restrict__ bvec,
    const float* __restrict__ Rw, const float* __restrict__ Rbvec,
    float* __restrict__ h, float* __restrict__ stats, int n) {
    __shared__ float As[BM][128];
    __shared__ float Xs[BM][128];
    __shared__ float bsum[128], bss[128];
    int tid = threadIdx.x;
    int m0 = blockIdx.x * BM;
    if (tid < 128) { bsum[tid] = 0.f; bss[tid] = 0.f; }
    // stage A tiles (agg and x) into LDS
    #pragma unroll
    for (int i = 0; i < 4; i++) {
        int idx = tid + i * 256;         // 0..1023 float4 slots
        int r = idx >> 5, c4 = idx & 31;
        int gr = m0 + r;
        float4 va = {0, 0, 0, 0}, vx = {0, 0, 0, 0};
        if (gr < n) {
            va = *(const float4*)&agg[(size_t)gr * 128 + c4 * 4];
            vx = *(const float4*)&x[(size_t)gr * 128 + c4 * 4];
        }
        *(float4*)&As[r][c4 * 4] = va;
        *(float4*)&Xs[r][c4 * 4] = vx;
    }
    __syncthreads();
    int rg = tid >> 5, cg = tid & 31;
    int r0 = rg * 4, c0 = cg * 4;
    float accA[4][4] = {}, accX[4][4] = {};
    for (int k = 0; k < 128; k += 4) {
        float4 a[4], xx[4], w[4], rw[4];
        #pragma unroll
        for (int i = 0; i < 4; i++) {
            a[i]  = *(const float4*)&As[r0 + i][k];
            xx[i] = *(const float4*)&Xs[r0 + i][k];
        }
        #pragma unroll
        for (int j = 0; j < 4; j++) {
            w[j]  = *(const float4*)&W[(k + j) * 128 + c0];
            rw[j] = *(const float4*)&Rw[(k + j) * 128 + c0];
        }
        #pragma unroll
        for (int i = 0; i < 4; i++) {
            const float* ap = (const float*)&a[i];
            const float* xp = (const float*)&xx[i];
            #pragma unroll
            for (int kk = 0; kk < 4; kk++) {
                const float* wp = (const float*)&w[kk];
                const float* rp = (const float*)&rw[kk];
                #pragma unroll
                for (int j = 0; j < 4; j++) {
                    accA[i][j] += ap[kk] * wp[j];
                    accX[i][j] += xp[kk] * rp[j];
                }
            }
        }
    }
    float4 bv  = *(const float4*)&bvec[c0];
    float4 rbv = *(const float4*)&Rbvec[c0];
    const float* bp  = (const float*)&bv;
    const float* rbp = (const float*)&rbv;
    float cs[4] = {0, 0, 0, 0}, css[4] = {0, 0, 0, 0};
    #pragma unroll
    for (int i = 0; i < 4; i++) {
        int gr = m0 + r0 + i;
        if (gr < n) {
            float4 out;
            float* op = (float*)&out;
            #pragma unroll
            for (int j = 0; j < 4; j++) {
                float hA = accA[i][j] + bp[j];  hA = hA > 0.f ? hA : 0.f;
                float hX = accX[i][j] + rbp[j]; hX = hX > 0.f ? hX : 0.f;
                float v = hA + hX;
                op[j] = v;
                cs[j] += v;
                css[j] += v * v;
            }
            *(float4*)&h[(size_t)gr * 128 + c0] = out;
        }
    }
    #pragma unroll
    for (int j = 0; j < 4; j++) {
        atomicAdd(&bsum[c0 + j], cs[j]);
        atomicAdd(&bss[c0 + j], css[j]);
    }
    __syncthreads();
    if (tid < 128) {
        float* sb = stats + (size_t)(blockIdx.x & 63) * 256;
        atomicAdd(&sb[tid], bsum[tid]);
        atomicAdd(&sb[tid + 128], bss[tid + 128 - 128 + 0 * 0] * 0.f + bss[tid]); // = bss[tid]
    }
}

__global__ void finalize_stats(const float* __restrict__ stats, const float* __restrict__ gamma,
                               const float* __restrict__ beta, float* __restrict__ ss, float n) {
    int c = threadIdx.x;  // 128 threads
    float s = 0.f, sq = 0.f;
    for (int b = 0; b < 64; b++) {
        s  += stats[b * 256 + c];
        sq += stats[b * 256 + c + 128];
    }
    float mu = s / n;
    float var = sq / n - mu * mu;
    float rstd = 1.0f / sqrtf(var + 1e-5f);
    float sc = gamma[c] * rstd;
    ss[c] = sc;
    ss[128 + c] = beta[c] - sc * mu;
}

__global__ void norm_apply(const float* __restrict__ h, const float* __restrict__ ss,
                           float* __restrict__ dstp, int total4) {
    int gid = blockIdx.x * blockDim.x + threadIdx.x;
    if (gid >= total4) return;
    int c4 = gid & 31;
    float4 sc = *(const float4*)&ss[c4 * 4];
    float4 sh = *(const float4*)&ss[128 + c4 * 4];
    float4 v = ((const float4*)h)[gid];
    float4 o;
    o.x = sc.x * v.x + sh.x;
    o.y = sc.y * v.y + sh.y;
    o.z = sc.z * v.z + sh.z;
    o.w = sc.w * v.w + sh.w;
    ((float4*)dstp)[gid] = o;
}

// ---------------- launch ----------------

extern "C" void kernel_launch(void* const* d_in, const int* in_sizes, int n_in,
                              void* d_out, int out_size, void* d_ws, size_t ws_size,
                              hipStream_t stream) {
    const int*   node_ids = (const int*)d_in[0];
    const int*   src      = (const int*)d_in[1];
    const int*   dst      = (const int*)d_in[2];
    const float* emb      = (const float*)d_in[3];
    const float* Ws       = (const float*)d_in[4];
    const float* bs       = (const float*)d_in[5];
    const float* Rws      = (const float*)d_in[6];
    const float* Rbs      = (const float*)d_in[7];
    const float* gammas   = (const float*)d_in[8];
    const float* betas    = (const float*)d_in[9];

    const int N = in_sizes[0];
    const int E = in_sizes[1];
    const int D = 128;
    const int L = in_sizes[4] / (D * D);

    // workspace layout
    size_t off = 0;
    auto alloc = [&](size_t bytes) -> void* {
        void* p = (char*)d_ws + off;
        off += (bytes + 255) & ~(size_t)255;
        return p;
    };
    int*   ints     = (int*)alloc((size_t)3 * N * 4);      // deg_src | deg_dst | cursor
    int*   deg_src  = ints;
    int*   deg_dst  = ints + N;
    int*   cursor   = ints + 2 * N;
    float* out_norm = (float*)alloc((size_t)N * 4);
    float* in_norm  = (float*)alloc((size_t)N * 4);
    int*   row_ptr  = (int*)alloc((size_t)(N + 1) * 4);
    int*   excl     = (int*)alloc((size_t)N * 4);
    int*   bsum     = (int*)alloc(64 * 4);
    int*   boff     = (int*)alloc(64 * 4);
    int*   col_idx  = (int*)alloc((size_t)E * 4);
    float* stats    = (float*)alloc((size_t)L * 64 * 256 * 4);
    float* ssbuf    = (float*)alloc(256 * 4);
    float* x        = (float*)alloc((size_t)N * D * 4);
    float* agg      = (float*)alloc((size_t)N * D * 4);
    float* h        = (float*)d_out;

    // 1. zero degree/cursor/stat accumulators
    init_zero<<<256, TPB, 0, stream>>>(ints, 3 * N, stats, L * 64 * 256);
    // 2. degrees
    degree_kernel<<<(E + TPB - 1) / TPB, TPB, 0, stream>>>(src, dst, deg_src, deg_dst, E);
    // 3. norms
    norm_kernel<<<(N + TPB - 1) / TPB, TPB, 0, stream>>>(deg_src, deg_dst, out_norm, in_norm, N);
    // 4. CSR build (by dst)
    int nb = (N + 1023) / 1024;
    scan1<<<nb, 1024, 0, stream>>>(deg_dst, excl, bsum, N);
    scan2<<<1, 64, 0, stream>>>(bsum, boff, nb);
    scan3<<<(N + 1 + TPB - 1) / TPB, TPB, 0, stream>>>(excl, boff, row_ptr, N, E);
    scatter_kernel<<<(E + TPB - 1) / TPB, TPB, 0, stream>>>(src, dst, row_ptr, cursor, col_idx, E);
    // 5. embedding gather
    embed_kernel<<<(N * 32 + TPB - 1) / TPB, TPB, 0, stream>>>(node_ids, emb, x, N);

    for (int l = 0; l < L; l++) {
        const float* W   = Ws  + (size_t)l * D * D;
        const float* b   = bs  + (size_t)l * D;
        const float* Rw  = Rws + (size_t)l * D * D;
        const float* Rb  = Rbs + (size_t)l * D;
        const float* gm  = gammas + (size_t)l * D;
        const float* bt  = betas  + (size_t)l * D;
        float* st = stats + (size_t)l * 64 * 256;

        agg_kernel<<<(N * 64 + TPB - 1) / TPB, TPB, 0, stream>>>(
            x, row_ptr, col_idx, out_norm, in_norm, agg, N);
        gemm_kernel<<<(N + BM - 1) / BM, TPB, 0, stream>>>(
            agg, x, W, b, Rw, Rb, h, st, N);
        finalize_stats<<<1, 128, 0, stream>>>(st, gm, bt, ssbuf, (float)N);
        float* dstp = (l < L - 1) ? x : (float*)d_out;
        norm_apply<<<(N * 32 + TPB - 1) / TPB, TPB, 0, stream>>>(h, ssbuf, dstp, N * 32);
    }
}

// Round 2
// 450.166 us; speedup vs baseline: 1.3610x; 1.3610x over previous
//
#include <hip/hip_runtime.h>
#include <hip/hip_bf16.h>

// GCN node encoder: 3 layers GraphConv(norm=both) + residual linear + ReLU + BatchNorm.
// N=50000, E=500000, D=128, L=3.
// Round 2: bf16 activations (x, agg) + bf16 MFMA GEMM (16x16x32), fp32 accumulate/stats.

#define TPB 256

typedef __attribute__((ext_vector_type(8))) short bf16x8;   // 8 bf16 = 4 VGPRs
typedef __attribute__((ext_vector_type(4))) float f32x4;

__device__ inline unsigned short f2bf(float f) {
    unsigned int u = __builtin_bit_cast(unsigned int, f);
    u += 0x7fff + ((u >> 16) & 1);          // RNE
    return (unsigned short)(u >> 16);
}
__device__ inline float bf2f(unsigned short b) {
    unsigned int u = ((unsigned int)b) << 16;
    return __builtin_bit_cast(float, u);
}

// ---------------- setup kernels ----------------

__global__ void init_zero(int* __restrict__ ints, int ni, float* __restrict__ fs, int nf) {
    int i = blockIdx.x * blockDim.x + threadIdx.x;
    int stride = gridDim.x * blockDim.x;
    for (int k = i; k < ni; k += stride) ints[k] = 0;
    for (int k = i; k < nf; k += stride) fs[k] = 0.f;
}

__global__ void degree_kernel(const int* __restrict__ src, const int* __restrict__ dst,
                              int* __restrict__ deg_src, int* __restrict__ deg_dst, int e) {
    int i = blockIdx.x * blockDim.x + threadIdx.x;
    if (i < e) {
        atomicAdd(&deg_src[src[i]], 1);
        atomicAdd(&deg_dst[dst[i]], 1);
    }
}

__global__ void norm_kernel(const int* __restrict__ deg_src, const int* __restrict__ deg_dst,
                            float* __restrict__ out_norm, float* __restrict__ in_norm, int n) {
    int v = blockIdx.x * blockDim.x + threadIdx.x;
    if (v < n) {
        int ds = deg_src[v];
        int dd = deg_dst[v];
        out_norm[v] = ds > 0 ? 1.0f / sqrtf((float)ds) : 0.0f;
        in_norm[v]  = dd > 0 ? 1.0f / sqrtf((float)dd) : 0.0f;
    }
}

__global__ void scan1(const int* __restrict__ deg, int* __restrict__ excl,
                      int* __restrict__ bsum, int n) {
    __shared__ int tmp[1024];
    int t = threadIdx.x;
    int i = blockIdx.x * 1024 + t;
    int v = (i < n) ? deg[i] : 0;
    tmp[t] = v;
    __syncthreads();
    for (int off = 1; off < 1024; off <<= 1) {
        int add = (t >= off) ? tmp[t - off] : 0;
        __syncthreads();
        tmp[t] += add;
        __syncthreads();
    }
    if (i < n) excl[i] = tmp[t] - v;
    if (t == 1023) bsum[blockIdx.x] = tmp[1023];
}

__global__ void scan2(const int* __restrict__ bsum, int* __restrict__ boff, int nb) {
    if (threadIdx.x == 0 && blockIdx.x == 0) {
        int run = 0;
        for (int i = 0; i < nb; i++) { boff[i] = run; run += bsum[i]; }
    }
}

__global__ void scan3(const int* __restrict__ excl, const int* __restrict__ boff,
                      int* __restrict__ row_ptr, int n, int e) {
    int i = blockIdx.x * blockDim.x + threadIdx.x;
    if (i < n) row_ptr[i] = excl[i] + boff[i >> 10];
    if (i == n) row_ptr[n] = e;
}

__global__ void scatter_kernel(const int* __restrict__ src, const int* __restrict__ dst,
                               const int* __restrict__ row_ptr, int* __restrict__ cursor,
                               int* __restrict__ col_idx, int e) {
    int i = blockIdx.x * blockDim.x + threadIdx.x;
    if (i < e) {
        int d = dst[i];
        int pos = row_ptr[d] + atomicAdd(&cursor[d], 1);
        col_idx[pos] = src[i];
    }
}

// x (bf16) = emb_table[node_ids]; thread handles 4 cols
__global__ void embed_kernel(const int* __restrict__ node_ids, const float* __restrict__ emb,
                             unsigned short* __restrict__ x, int n) {
    int gid = blockIdx.x * blockDim.x + threadIdx.x;
    if (gid >= n * 32) return;
    int v = gid >> 5, c4 = gid & 31;
    int id = node_ids[v];
    float4 e = *(const float4*)&emb[id * 128 + c4 * 4];
    ushort4 o;
    o.x = f2bf(e.x); o.y = f2bf(e.y); o.z = f2bf(e.z); o.w = f2bf(e.w);
    *(ushort4*)&x[(size_t)v * 128 + c4 * 4] = o;
}

// transpose + bf16-convert weights: Wt[l][nrow][k] = W[l][k][nrow]
__global__ void prep_weights(const float* __restrict__ Ws, const float* __restrict__ Rws,
                             unsigned short* __restrict__ Wt, unsigned short* __restrict__ Rwt,
                             int total) {
    int i = blockIdx.x * blockDim.x + threadIdx.x;
    if (i >= total) return;
    int l = i >> 14, r = (i >> 7) & 127, k = i & 127;
    int sidx = l * 16384 + k * 128 + r;
    Wt[i]  = f2bf(Ws[sidx]);
    Rwt[i] = f2bf(Rws[sidx]);
}

// ---------------- per-layer kernels ----------------

// one wave per destination node; lane holds 2 bf16 feature cols (4 B loads)
__global__ void agg_kernel(const unsigned short* __restrict__ x, const int* __restrict__ row_ptr,
                           const int* __restrict__ col_idx, const float* __restrict__ out_norm,
                           const float* __restrict__ in_norm, unsigned short* __restrict__ agg,
                           int n) {
    int gtid = blockIdx.x * blockDim.x + threadIdx.x;
    int node = gtid >> 6;
    int lane = threadIdx.x & 63;
    if (node >= n) return;
    int beg = row_ptr[node], end = row_ptr[node + 1];
    float ax = 0.f, ay = 0.f;
    int i = beg;
    for (; i + 1 < end; i += 2) {
        int u0 = col_idx[i], u1 = col_idx[i + 1];
        float n0 = out_norm[u0], n1 = out_norm[u1];
        unsigned int p0 = *(const unsigned int*)&x[(size_t)u0 * 128 + lane * 2];
        unsigned int p1 = *(const unsigned int*)&x[(size_t)u1 * 128 + lane * 2];
        ax += n0 * bf2f((unsigned short)p0) + n1 * bf2f((unsigned short)p1);
        ay += n0 * bf2f((unsigned short)(p0 >> 16)) + n1 * bf2f((unsigned short)(p1 >> 16));
    }
    if (i < end) {
        int u = col_idx[i];
        float nn = out_norm[u];
        unsigned int p = *(const unsigned int*)&x[(size_t)u * 128 + lane * 2];
        ax += nn * bf2f((unsigned short)p);
        ay += nn * bf2f((unsigned short)(p >> 16));
    }
    float inv = in_norm[node];
    ax *= inv; ay *= inv;
    unsigned int packed = (unsigned int)f2bf(ax) | ((unsigned int)f2bf(ay) << 16);
    *(unsigned int*)&agg[(size_t)node * 128 + lane * 2] = packed;
}

// h = relu(agg@W + b) + relu(x@Rw + Rb), fp32 out; fused BN sum/sumsq accumulation.
// MFMA 16x16x32 bf16. Block: 256 thr = 4 waves; tile M=64, N=128, K=128.
#define GM 64
#define APAD 136   // 128 + 8 shorts: 272 B row stride -> bank stride 4 -> 2-way (free)
__global__ __launch_bounds__(256) void gemm_kernel(
    const unsigned short* __restrict__ agg, const unsigned short* __restrict__ x,
    const unsigned short* __restrict__ Wt, const unsigned short* __restrict__ Rwt,
    const float* __restrict__ bvec, const float* __restrict__ Rbvec,
    float* __restrict__ h, float* __restrict__ stats, int nrows) {
    __shared__ unsigned short As[GM * APAD];
    __shared__ unsigned short Xs[GM * APAD];
    __shared__ float bsum[128], bss[128];
    int tid = threadIdx.x;
    int m0 = blockIdx.x * GM;
    if (tid < 128) { bsum[tid] = 0.f; bss[tid] = 0.f; }
    // stage A tiles: 64 rows x 16 chunks of 16 B each, per array
    #pragma unroll
    for (int i = 0; i < 4; i++) {
        int c = tid + i * 256;
        int r = c >> 4, c16 = c & 15;
        int gr = m0 + r;
        uint4 va = {0, 0, 0, 0}, vx = {0, 0, 0, 0};
        if (gr < nrows) {
            va = *(const uint4*)&agg[(size_t)gr * 128 + c16 * 8];
            vx = *(const uint4*)&x[(size_t)gr * 128 + c16 * 8];
        }
        *(uint4*)&As[r * APAD + c16 * 8] = va;
        *(uint4*)&Xs[r * APAD + c16 * 8] = vx;
    }
    __syncthreads();

    int wave = tid >> 6;
    int lane = tid & 63;
    int m = lane & 15;
    int quad = lane >> 4;
    int r0 = wave * 16;

    f32x4 accA[8], accX[8];
    #pragma unroll
    for (int t = 0; t < 8; t++) { accA[t] = (f32x4){0,0,0,0}; accX[t] = (f32x4){0,0,0,0}; }

    #pragma unroll
    for (int kc = 0; kc < 4; kc++) {
        int koff = kc * 32 + quad * 8;
        bf16x8 aA = *(const bf16x8*)&As[(r0 + m) * APAD + koff];
        bf16x8 aX = *(const bf16x8*)&Xs[(r0 + m) * APAD + koff];
        #pragma unroll
        for (int nt = 0; nt < 8; nt++) {
            int nrow = nt * 16 + m;
            bf16x8 bW = *(const bf16x8*)&Wt[(size_t)nrow * 128 + koff];
            bf16x8 bR = *(const bf16x8*)&Rwt[(size_t)nrow * 128 + koff];
            accA[nt] = __builtin_amdgcn_mfma_f32_16x16x32_bf16(aA, bW, accA[nt], 0, 0, 0);
            accX[nt] = __builtin_amdgcn_mfma_f32_16x16x32_bf16(aX, bR, accX[nt], 0, 0, 0);
        }
    }

    // epilogue: bias + relu + add; write h; per-column stats
    #pragma unroll
    for (int nt = 0; nt < 8; nt++) {
        int col = nt * 16 + m;
        float bW = bvec[col], bR = Rbvec[col];
        float cs = 0.f, cq = 0.f;
        #pragma unroll
        for (int reg = 0; reg < 4; reg++) {
            int gr = m0 + r0 + quad * 4 + reg;
            float hA = accA[nt][reg] + bW; hA = hA > 0.f ? hA : 0.f;
            float hX = accX[nt][reg] + bR; hX = hX > 0.f ? hX : 0.f;
            float v = hA + hX;
            if (gr < nrows) {
                h[(size_t)gr * 128 + col] = v;
            } else {
                v = 0.f;
            }
            cs += v; cq += v * v;
        }
        cs += __shfl_xor(cs, 16); cs += __shfl_xor(cs, 32);
        cq += __shfl_xor(cq, 16); cq += __shfl_xor(cq, 32);
        if (lane < 16) {
            atomicAdd(&bsum[col], cs);
            atomicAdd(&bss[col], cq);
        }
    }
    __syncthreads();
    if (tid < 128) {
        float* sb = stats + (size_t)(blockIdx.x & 63) * 256;
        atomicAdd(&sb[tid], bsum[tid]);
        atomicAdd(&sb[tid + 128], bss[tid]);
    }
}

__global__ void finalize_stats(const float* __restrict__ stats, const float* __restrict__ gamma,
                               const float* __restrict__ beta, float* __restrict__ ss, float n) {
    int c = threadIdx.x;  // 128 threads
    float s = 0.f, sq = 0.f;
    for (int b = 0; b < 64; b++) {
        s  += stats[b * 256 + c];
        sq += stats[b * 256 + c + 128];
    }
    float mu = s / n;
    float var = sq / n - mu * mu;
    float rstd = 1.0f / sqrtf(var + 1e-5f);
    float sc = gamma[c] * rstd;
    ss[c] = sc;
    ss[128 + c] = beta[c] - sc * mu;
}

// intermediate layers: write bf16 x for the next layer
__global__ void norm_apply_bf16(const float* __restrict__ h, const float* __restrict__ ss,
                                unsigned short* __restrict__ dstp, int total4) {
    int gid = blockIdx.x * blockDim.x + threadIdx.x;
    if (gid >= total4) return;
    int c4 = gid & 31;
    float4 sc = *(const float4*)&ss[c4 * 4];
    float4 sh = *(const float4*)&ss[128 + c4 * 4];
    float4 v = ((const float4*)h)[gid];
    ushort4 o;
    o.x = f2bf(sc.x * v.x + sh.x);
    o.y = f2bf(sc.y * v.y + sh.y);
    o.z = f2bf(sc.z * v.z + sh.z);
    o.w = f2bf(sc.w * v.w + sh.w);
    ((ushort4*)dstp)[gid] = o;
}

// final layer: fp32 out
__global__ void norm_apply_f32(const float* __restrict__ h, const float* __restrict__ ss,
                               float* __restrict__ dstp, int total4) {
    int gid = blockIdx.x * blockDim.x + threadIdx.x;
    if (gid >= total4) return;
    int c4 = gid & 31;
    float4 sc = *(const float4*)&ss[c4 * 4];
    float4 sh = *(const float4*)&ss[128 + c4 * 4];
    float4 v = ((const float4*)h)[gid];
    float4 o;
    o.x = sc.x * v.x + sh.x;
    o.y = sc.y * v.y + sh.y;
    o.z = sc.z * v.z + sh.z;
    o.w = sc.w * v.w + sh.w;
    ((float4*)dstp)[gid] = o;
}

// ---------------- launch ----------------

extern "C" void kernel_launch(void* const* d_in, const int* in_sizes, int n_in,
                              void* d_out, int out_size, void* d_ws, size_t ws_size,
                              hipStream_t stream) {
    const int*   node_ids = (const int*)d_in[0];
    const int*   src      = (const int*)d_in[1];
    const int*   dst      = (const int*)d_in[2];
    const float* emb      = (const float*)d_in[3];
    const float* Ws       = (const float*)d_in[4];
    const float* bs       = (const float*)d_in[5];
    const float* Rws      = (const float*)d_in[6];
    const float* Rbs      = (const float*)d_in[7];
    const float* gammas   = (const float*)d_in[8];
    const float* betas    = (const float*)d_in[9];

    const int N = in_sizes[0];
    const int E = in_sizes[1];
    const int D = 128;
    const int L = in_sizes[4] / (D * D);

    size_t off = 0;
    auto alloc = [&](size_t bytes) -> void* {
        void* p = (char*)d_ws + off;
        off += (bytes + 255) & ~(size_t)255;
        return p;
    };
    int*   ints     = (int*)alloc((size_t)3 * N * 4);   // deg_src | deg_dst | cursor
    int*   deg_src  = ints;
    int*   deg_dst  = ints + N;
    int*   cursor   = ints + 2 * N;
    float* out_norm = (float*)alloc((size_t)N * 4);
    float* in_norm  = (float*)alloc((size_t)N * 4);
    int*   row_ptr  = (int*)alloc((size_t)(N + 1) * 4);
    int*   excl     = (int*)alloc((size_t)N * 4);
    int*   bsum     = (int*)alloc(64 * 4);
    int*   boff     = (int*)alloc(64 * 4);
    int*   col_idx  = (int*)alloc((size_t)E * 4);
    float* stats    = (float*)alloc((size_t)L * 64 * 256 * 4);
    float* ssbuf    = (float*)alloc(256 * 4);
    unsigned short* Wt  = (unsigned short*)alloc((size_t)L * D * D * 2);
    unsigned short* Rwt = (unsigned short*)alloc((size_t)L * D * D * 2);
    unsigned short* x   = (unsigned short*)alloc((size_t)N * D * 2);
    unsigned short* agg = (unsigned short*)alloc((size_t)N * D * 2);
    float* h = (float*)d_out;  // reuse output buffer as the fp32 h scratch

    init_zero<<<256, TPB, 0, stream>>>(ints, 3 * N, stats, L * 64 * 256);
    degree_kernel<<<(E + TPB - 1) / TPB, TPB, 0, stream>>>(src, dst, deg_src, deg_dst, E);
    norm_kernel<<<(N + TPB - 1) / TPB, TPB, 0, stream>>>(deg_src, deg_dst, out_norm, in_norm, N);
    int nb = (N + 1023) / 1024;
    scan1<<<nb, 1024, 0, stream>>>(deg_dst, excl, bsum, N);
    scan2<<<1, 64, 0, stream>>>(bsum, boff, nb);
    scan3<<<(N + 1 + TPB - 1) / TPB, TPB, 0, stream>>>(excl, boff, row_ptr, N, E);
    scatter_kernel<<<(E + TPB - 1) / TPB, TPB, 0, stream>>>(src, dst, row_ptr, cursor, col_idx, E);
    embed_kernel<<<(N * 32 + TPB - 1) / TPB, TPB, 0, stream>>>(node_ids, emb, x, N);
    prep_weights<<<(L * D * D + TPB - 1) / TPB, TPB, 0, stream>>>(Ws, Rws, Wt, Rwt, L * D * D);

    for (int l = 0; l < L; l++) {
        const unsigned short* Wtl  = Wt  + (size_t)l * D * D;
        const unsigned short* Rwtl = Rwt + (size_t)l * D * D;
        const float* b   = bs  + (size_t)l * D;
        const float* Rb  = Rbs + (size_t)l * D;
        const float* gm  = gammas + (size_t)l * D;
        const float* bt  = betas  + (size_t)l * D;
        float* st = stats + (size_t)l * 64 * 256;

        agg_kernel<<<((size_t)N * 64 + TPB - 1) / TPB, TPB, 0, stream>>>(
            x, row_ptr, col_idx, out_norm, in_norm, agg, N);
        gemm_kernel<<<(N + GM - 1) / GM, TPB, 0, stream>>>(
            agg, x, Wtl, Rwtl, b, Rb, h, st, N);
        finalize_stats<<<1, 128, 0, stream>>>(st, gm, bt, ssbuf, (float)N);
        if (l < L - 1) {
            norm_apply_bf16<<<(N * 32 + TPB - 1) / TPB, TPB, 0, stream>>>(h, ssbuf, x, N * 32);
        } else {
            norm_apply_f32<<<(N * 32 + TPB - 1) / TPB, TPB, 0, stream>>>(h, ssbuf, (float*)d_out, N * 32);
        }
    }
}

// Round 3
// 431.003 us; speedup vs baseline: 1.4215x; 1.0445x over previous
//
#include <hip/hip_runtime.h>
#include <hip/hip_bf16.h>

// GCN node encoder: 3 layers GraphConv(norm=both) + residual linear + ReLU + BatchNorm.
// N=50000, E=500000, D=128, L=3.
// Round 3: fuse gather(agg) + dual GEMM + BN-stat into one kernel per layer.
//   - gather: 4 threads/node, 32 cols each -> 64 independent load chains per wave (MLP fix)
//   - conv A-frag from LDS; residual A-frag direct from global x (L2-resident)
//   - removes agg global round-trip (25.6 MB/layer) and one dispatch per layer

#define TPB 256

typedef __attribute__((ext_vector_type(8))) short bf16x8;   // 8 bf16 = 4 VGPRs
typedef __attribute__((ext_vector_type(4))) float f32x4;

__device__ inline unsigned short f2bf(float f) {
    unsigned int u = __builtin_bit_cast(unsigned int, f);
    u += 0x7fff + ((u >> 16) & 1);          // RNE
    return (unsigned short)(u >> 16);
}
__device__ inline float bf2f(unsigned short b) {
    unsigned int u = ((unsigned int)b) << 16;
    return __builtin_bit_cast(float, u);
}

// ---------------- setup kernels ----------------

__global__ void init_zero(int* __restrict__ ints, int ni, float* __restrict__ fs, int nf) {
    int i = blockIdx.x * blockDim.x + threadIdx.x;
    int stride = gridDim.x * blockDim.x;
    for (int k = i; k < ni; k += stride) ints[k] = 0;
    for (int k = i; k < nf; k += stride) fs[k] = 0.f;
}

__global__ void degree_kernel(const int* __restrict__ src, const int* __restrict__ dst,
                              int* __restrict__ deg_src, int* __restrict__ deg_dst, int e) {
    int i = blockIdx.x * blockDim.x + threadIdx.x;
    if (i < e) {
        atomicAdd(&deg_src[src[i]], 1);
        atomicAdd(&deg_dst[dst[i]], 1);
    }
}

__global__ void norm_kernel(const int* __restrict__ deg_src, const int* __restrict__ deg_dst,
                            float* __restrict__ out_norm, float* __restrict__ in_norm, int n) {
    int v = blockIdx.x * blockDim.x + threadIdx.x;
    if (v < n) {
        int ds = deg_src[v];
        int dd = deg_dst[v];
        out_norm[v] = ds > 0 ? 1.0f / sqrtf((float)ds) : 0.0f;
        in_norm[v]  = dd > 0 ? 1.0f / sqrtf((float)dd) : 0.0f;
    }
}

__global__ void scan1(const int* __restrict__ deg, int* __restrict__ excl,
                      int* __restrict__ bsum, int n) {
    __shared__ int tmp[1024];
    int t = threadIdx.x;
    int i = blockIdx.x * 1024 + t;
    int v = (i < n) ? deg[i] : 0;
    tmp[t] = v;
    __syncthreads();
    for (int off = 1; off < 1024; off <<= 1) {
        int add = (t >= off) ? tmp[t - off] : 0;
        __syncthreads();
        tmp[t] += add;
        __syncthreads();
    }
    if (i < n) excl[i] = tmp[t] - v;
    if (t == 1023) bsum[blockIdx.x] = tmp[1023];
}

__global__ void scan2(const int* __restrict__ bsum, int* __restrict__ boff, int nb) {
    if (threadIdx.x == 0 && blockIdx.x == 0) {
        int run = 0;
        for (int i = 0; i < nb; i++) { boff[i] = run; run += bsum[i]; }
    }
}

__global__ void scan3(const int* __restrict__ excl, const int* __restrict__ boff,
                      int* __restrict__ row_ptr, int n, int e) {
    int i = blockIdx.x * blockDim.x + threadIdx.x;
    if (i < n) row_ptr[i] = excl[i] + boff[i >> 10];
    if (i == n) row_ptr[n] = e;
}

__global__ void scatter_kernel(const int* __restrict__ src, const int* __restrict__ dst,
                               const int* __restrict__ row_ptr, int* __restrict__ cursor,
                               int* __restrict__ col_idx, int e) {
    int i = blockIdx.x * blockDim.x + threadIdx.x;
    if (i < e) {
        int d = dst[i];
        int pos = row_ptr[d] + atomicAdd(&cursor[d], 1);
        col_idx[pos] = src[i];
    }
}

// x (bf16) = emb_table[node_ids]
__global__ void embed_kernel(const int* __restrict__ node_ids, const float* __restrict__ emb,
                             unsigned short* __restrict__ x, int n) {
    int gid = blockIdx.x * blockDim.x + threadIdx.x;
    if (gid >= n * 32) return;
    int v = gid >> 5, c4 = gid & 31;
    int id = node_ids[v];
    float4 e = *(const float4*)&emb[id * 128 + c4 * 4];
    ushort4 o;
    o.x = f2bf(e.x); o.y = f2bf(e.y); o.z = f2bf(e.z); o.w = f2bf(e.w);
    *(ushort4*)&x[(size_t)v * 128 + c4 * 4] = o;
}

// transpose + bf16-convert weights: Wt[l][nrow][k] = W[l][k][nrow]
__global__ void prep_weights(const float* __restrict__ Ws, const float* __restrict__ Rws,
                             unsigned short* __restrict__ Wt, unsigned short* __restrict__ Rwt,
                             int total) {
    int i = blockIdx.x * blockDim.x + threadIdx.x;
    if (i >= total) return;
    int l = i >> 14, r = (i >> 7) & 127, k = i & 127;
    int sidx = l * 16384 + k * 128 + r;
    Wt[i]  = f2bf(Ws[sidx]);
    Rwt[i] = f2bf(Rws[sidx]);
}

// ---------------- fused per-layer kernel ----------------
// Phase 1 (gather): 256 thr = 4 thr/node x 64 nodes; each thread owns 32 cols,
//   walks the node's neighbor list with an independent load chain, accumulates
//   fp32, writes bf16 into LDS As.
// Phase 2 (MFMA): 4 waves; wave w does rows w*16..w*16+15, all 128 cols.
//   conv A-frag from LDS As; residual A-frag direct global from x; B from Wt/Rwt.
// Epilogue: bias+relu+add -> h (fp32), BN sum/sumsq -> 64-banked global stats.
#define GM 64
#define APAD 136   // 128+8 shorts: 272 B row stride
__global__ __launch_bounds__(256) void fused_layer_kernel(
    const unsigned short* __restrict__ x,
    const int* __restrict__ row_ptr, const int* __restrict__ col_idx,
    const float* __restrict__ out_norm, const float* __restrict__ in_norm,
    const unsigned short* __restrict__ Wt, const unsigned short* __restrict__ Rwt,
    const float* __restrict__ bvec, const float* __restrict__ Rbvec,
    float* __restrict__ h, float* __restrict__ stats, int nrows) {
    __shared__ unsigned short As[GM * APAD];
    __shared__ float bsum[128], bss[128];
    int tid = threadIdx.x;
    int m0 = blockIdx.x * GM;
    if (tid < 128) { bsum[tid] = 0.f; bss[tid] = 0.f; }

    // ---- phase 1: gather ----
    {
        int node = tid >> 2;
        int part = tid & 3;
        int gnode = m0 + node;
        float acc[32];
        #pragma unroll
        for (int j = 0; j < 32; j++) acc[j] = 0.f;
        if (gnode < nrows) {
            int beg = row_ptr[gnode], end = row_ptr[gnode + 1];
            const unsigned short* xb = x + part * 32;
            if (beg < end) {
                int u = col_idx[beg];
                for (int e = beg;;) {
                    int unext = (e + 1 < end) ? col_idx[e + 1] : 0;  // prefetch idx
                    float nn = out_norm[u];
                    const uint4* p = (const uint4*)(xb + (size_t)u * 128);
                    uint4 q0 = p[0], q1 = p[1], q2 = p[2], q3 = p[3];
                    unsigned int w[16] = {q0.x, q0.y, q0.z, q0.w, q1.x, q1.y, q1.z, q1.w,
                                          q2.x, q2.y, q2.z, q2.w, q3.x, q3.y, q3.z, q3.w};
                    #pragma unroll
                    for (int t = 0; t < 16; t++) {
                        acc[2 * t]     += nn * bf2f((unsigned short)w[t]);
                        acc[2 * t + 1] += nn * bf2f((unsigned short)(w[t] >> 16));
                    }
                    if (++e >= end) break;
                    u = unext;
                }
            }
            float inv = in_norm[gnode];
            #pragma unroll
            for (int j = 0; j < 32; j++) acc[j] *= inv;
        }
        unsigned short* dstp = &As[node * APAD + part * 32];
        #pragma unroll
        for (int j = 0; j < 16; j++) {
            unsigned int pk = (unsigned int)f2bf(acc[2 * j]) |
                              ((unsigned int)f2bf(acc[2 * j + 1]) << 16);
            *(unsigned int*)&dstp[2 * j] = pk;
        }
    }
    __syncthreads();

    // ---- phase 2: dual GEMM via MFMA 16x16x32 bf16 ----
    int wave = tid >> 6;
    int lane = tid & 63;
    int m = lane & 15;
    int quad = lane >> 4;
    int r0 = wave * 16;
    int grx = m0 + r0 + m;
    if (grx >= nrows) grx = nrows - 1;   // clamp; results for OOB rows discarded

    f32x4 accA[8], accX[8];
    #pragma unroll
    for (int t = 0; t < 8; t++) { accA[t] = (f32x4){0,0,0,0}; accX[t] = (f32x4){0,0,0,0}; }

    #pragma unroll
    for (int kc = 0; kc < 4; kc++) {
        int koff = kc * 32 + quad * 8;
        bf16x8 aA = *(const bf16x8*)&As[(r0 + m) * APAD + koff];
        bf16x8 aX = *(const bf16x8*)&x[(size_t)grx * 128 + koff];
        #pragma unroll
        for (int nt = 0; nt < 8; nt++) {
            int nrow = nt * 16 + m;
            bf16x8 bW = *(const bf16x8*)&Wt[(size_t)nrow * 128 + koff];
            bf16x8 bR = *(const bf16x8*)&Rwt[(size_t)nrow * 128 + koff];
            accA[nt] = __builtin_amdgcn_mfma_f32_16x16x32_bf16(aA, bW, accA[nt], 0, 0, 0);
            accX[nt] = __builtin_amdgcn_mfma_f32_16x16x32_bf16(aX, bR, accX[nt], 0, 0, 0);
        }
    }

    // ---- epilogue ----
    #pragma unroll
    for (int nt = 0; nt < 8; nt++) {
        int col = nt * 16 + m;
        float bW = bvec[col], bR = Rbvec[col];
        float cs = 0.f, cq = 0.f;
        #pragma unroll
        for (int reg = 0; reg < 4; reg++) {
            int gr = m0 + r0 + quad * 4 + reg;
            float hA = accA[nt][reg] + bW; hA = hA > 0.f ? hA : 0.f;
            float hX = accX[nt][reg] + bR; hX = hX > 0.f ? hX : 0.f;
            float v = hA + hX;
            if (gr < nrows) {
                h[(size_t)gr * 128 + col] = v;
            } else {
                v = 0.f;
            }
            cs += v; cq += v * v;
        }
        cs += __shfl_xor(cs, 16); cs += __shfl_xor(cs, 32);
        cq += __shfl_xor(cq, 16); cq += __shfl_xor(cq, 32);
        if (lane < 16) {
            atomicAdd(&bsum[col], cs);
            atomicAdd(&bss[col], cq);
        }
    }
    __syncthreads();
    if (tid < 128) {
        float* sb = stats + (size_t)(blockIdx.x & 63) * 256;
        atomicAdd(&sb[tid], bsum[tid]);
        atomicAdd(&sb[tid + 128], bss[tid]);
    }
}

__global__ void finalize_stats(const float* __restrict__ stats, const float* __restrict__ gamma,
                               const float* __restrict__ beta, float* __restrict__ ss, float n) {
    int c = threadIdx.x;  // 128 threads
    float s = 0.f, sq = 0.f;
    for (int b = 0; b < 64; b++) {
        s  += stats[b * 256 + c];
        sq += stats[b * 256 + c + 128];
    }
    float mu = s / n;
    float var = sq / n - mu * mu;
    float rstd = 1.0f / sqrtf(var + 1e-5f);
    float sc = gamma[c] * rstd;
    ss[c] = sc;
    ss[128 + c] = beta[c] - sc * mu;
}

// intermediate layers: write bf16 x for the next layer
__global__ void norm_apply_bf16(const float* __restrict__ h, const float* __restrict__ ss,
                                unsigned short* __restrict__ dstp, int total4) {
    int gid = blockIdx.x * blockDim.x + threadIdx.x;
    if (gid >= total4) return;
    int c4 = gid & 31;
    float4 sc = *(const float4*)&ss[c4 * 4];
    float4 sh = *(const float4*)&ss[128 + c4 * 4];
    float4 v = ((const float4*)h)[gid];
    ushort4 o;
    o.x = f2bf(sc.x * v.x + sh.x);
    o.y = f2bf(sc.y * v.y + sh.y);
    o.z = f2bf(sc.z * v.z + sh.z);
    o.w = f2bf(sc.w * v.w + sh.w);
    ((ushort4*)dstp)[gid] = o;
}

// final layer: fp32 out
__global__ void norm_apply_f32(const float* __restrict__ h, const float* __restrict__ ss,
                               float* __restrict__ dstp, int total4) {
    int gid = blockIdx.x * blockDim.x + threadIdx.x;
    if (gid >= total4) return;
    int c4 = gid & 31;
    float4 sc = *(const float4*)&ss[c4 * 4];
    float4 sh = *(const float4*)&ss[128 + c4 * 4];
    float4 v = ((const float4*)h)[gid];
    float4 o;
    o.x = sc.x * v.x + sh.x;
    o.y = sc.y * v.y + sh.y;
    o.z = sc.z * v.z + sh.z;
    o.w = sc.w * v.w + sh.w;
    ((float4*)dstp)[gid] = o;
}

// ---------------- launch ----------------

extern "C" void kernel_launch(void* const* d_in, const int* in_sizes, int n_in,
                              void* d_out, int out_size, void* d_ws, size_t ws_size,
                              hipStream_t stream) {
    const int*   node_ids = (const int*)d_in[0];
    const int*   src      = (const int*)d_in[1];
    const int*   dst      = (const int*)d_in[2];
    const float* emb      = (const float*)d_in[3];
    const float* Ws       = (const float*)d_in[4];
    const float* bs       = (const float*)d_in[5];
    const float* Rws      = (const float*)d_in[6];
    const float* Rbs      = (const float*)d_in[7];
    const float* gammas   = (const float*)d_in[8];
    const float* betas    = (const float*)d_in[9];

    const int N = in_sizes[0];
    const int E = in_sizes[1];
    const int D = 128;
    const int L = in_sizes[4] / (D * D);

    size_t off = 0;
    auto alloc = [&](size_t bytes) -> void* {
        void* p = (char*)d_ws + off;
        off += (bytes + 255) & ~(size_t)255;
        return p;
    };
    int*   ints     = (int*)alloc((size_t)3 * N * 4);   // deg_src | deg_dst | cursor
    int*   deg_src  = ints;
    int*   deg_dst  = ints + N;
    int*   cursor   = ints + 2 * N;
    float* out_norm = (float*)alloc((size_t)N * 4);
    float* in_norm  = (float*)alloc((size_t)N * 4);
    int*   row_ptr  = (int*)alloc((size_t)(N + 1) * 4);
    int*   excl     = (int*)alloc((size_t)N * 4);
    int*   bsum     = (int*)alloc(64 * 4);
    int*   boff     = (int*)alloc(64 * 4);
    int*   col_idx  = (int*)alloc((size_t)E * 4);
    float* stats    = (float*)alloc((size_t)L * 64 * 256 * 4);
    float* ssbuf    = (float*)alloc(256 * 4);
    unsigned short* Wt  = (unsigned short*)alloc((size_t)L * D * D * 2);
    unsigned short* Rwt = (unsigned short*)alloc((size_t)L * D * D * 2);
    unsigned short* x   = (unsigned short*)alloc((size_t)N * D * 2);
    float* h = (float*)d_out;  // reuse output buffer as the fp32 h scratch

    init_zero<<<256, TPB, 0, stream>>>(ints, 3 * N, stats, L * 64 * 256);
    degree_kernel<<<(E + TPB - 1) / TPB, TPB, 0, stream>>>(src, dst, deg_src, deg_dst, E);
    norm_kernel<<<(N + TPB - 1) / TPB, TPB, 0, stream>>>(deg_src, deg_dst, out_norm, in_norm, N);
    int nb = (N + 1023) / 1024;
    scan1<<<nb, 1024, 0, stream>>>(deg_dst, excl, bsum, N);
    scan2<<<1, 64, 0, stream>>>(bsum, boff, nb);
    scan3<<<(N + 1 + TPB - 1) / TPB, TPB, 0, stream>>>(excl, boff, row_ptr, N, E);
    scatter_kernel<<<(E + TPB - 1) / TPB, TPB, 0, stream>>>(src, dst, row_ptr, cursor, col_idx, E);
    embed_kernel<<<(N * 32 + TPB - 1) / TPB, TPB, 0, stream>>>(node_ids, emb, x, N);
    prep_weights<<<(L * D * D + TPB - 1) / TPB, TPB, 0, stream>>>(Ws, Rws, Wt, Rwt, L * D * D);

    int gblocks = (N + GM - 1) / GM;
    for (int l = 0; l < L; l++) {
        const unsigned short* Wtl  = Wt  + (size_t)l * D * D;
        const unsigned short* Rwtl = Rwt + (size_t)l * D * D;
        const float* b   = bs  + (size_t)l * D;
        const float* Rb  = Rbs + (size_t)l * D;
        const float* gm  = gammas + (size_t)l * D;
        const float* bt  = betas  + (size_t)l * D;
        float* st = stats + (size_t)l * 64 * 256;

        fused_layer_kernel<<<gblocks, TPB, 0, stream>>>(
            x, row_ptr, col_idx, out_norm, in_norm, Wtl, Rwtl, b, Rb, h, st, N);
        finalize_stats<<<1, 128, 0, stream>>>(st, gm, bt, ssbuf, (float)N);
        if (l < L - 1) {
            norm_apply_bf16<<<(N * 32 + TPB - 1) / TPB, TPB, 0, stream>>>(h, ssbuf, x, N * 32);
        } else {
            norm_apply_f32<<<(N * 32 + TPB - 1) / TPB, TPB, 0, stream>>>(h, ssbuf, (float*)d_out, N * 32);
        }
    }
}

// Round 4
// 381.815 us; speedup vs baseline: 1.6046x; 1.1288x over previous
//
#include <hip/hip_runtime.h>
#include <hip/hip_bf16.h>

// GCN node encoder: 3 layers GraphConv(norm=both) + residual linear + ReLU + BatchNorm.
// N=50000, E=500000, D=128, L=3.
// Round 4: 4-edge-batched gather (16 loads in flight/lane), atomic-free scatter via
// rank-from-degree-pass, merged prep kernels, finalize folded into norm_apply.

#define TPB 256
#define NBANK 8   // stat accumulator banks

typedef __attribute__((ext_vector_type(8))) short bf16x8;   // 8 bf16 = 4 VGPRs
typedef __attribute__((ext_vector_type(4))) float f32x4;

__device__ inline unsigned short f2bf(float f) {
    unsigned int u = __builtin_bit_cast(unsigned int, f);
    u += 0x7fff + ((u >> 16) & 1);          // RNE
    return (unsigned short)(u >> 16);
}
__device__ inline float bf2f(unsigned short b) {
    unsigned int u = ((unsigned int)b) << 16;
    return __builtin_bit_cast(float, u);
}

// ---------------- setup kernels ----------------

// degrees + per-edge rank (old value of dst-degree counter)
__global__ void degree_kernel(const int* __restrict__ src, const int* __restrict__ dst,
                              int* __restrict__ deg_src, int* __restrict__ deg_dst,
                              int* __restrict__ rank, int e) {
    int i = blockIdx.x * blockDim.x + threadIdx.x;
    if (i < e) {
        atomicAdd(&deg_src[src[i]], 1);
        rank[i] = atomicAdd(&deg_dst[dst[i]], 1);
    }
}

// block-local exclusive scan of deg_dst into row_ptr, block sums to bsum; also norms
__global__ void scan1_norm(const int* __restrict__ deg_src, const int* __restrict__ deg_dst,
                           float* __restrict__ out_norm, float* __restrict__ in_norm,
                           int* __restrict__ row_ptr, int* __restrict__ bsum, int n) {
    __shared__ int tmp[1024];
    int t = threadIdx.x;
    int i = blockIdx.x * 1024 + t;
    int v = (i < n) ? deg_dst[i] : 0;
    tmp[t] = v;
    __syncthreads();
    for (int off = 1; off < 1024; off <<= 1) {
        int add = (t >= off) ? tmp[t - off] : 0;
        __syncthreads();
        tmp[t] += add;
        __syncthreads();
    }
    if (i < n) {
        row_ptr[i] = tmp[t] - v;
        int dsv = deg_src[i];
        out_norm[i] = dsv > 0 ? rsqrtf((float)dsv) : 0.f;
        in_norm[i]  = v   > 0 ? rsqrtf((float)v)   : 0.f;
    }
    if (t == 1023) bsum[blockIdx.x] = tmp[1023];
}

// add block offset (computed inline from bsum) in place; set row_ptr[n]=e
__global__ void scan_apply(const int* __restrict__ bsum, int* __restrict__ row_ptr,
                           int n, int e) {
    __shared__ int boff;
    if (threadIdx.x == 0) {
        int r = 0;
        for (int b2 = 0; b2 < blockIdx.x; b2++) r += bsum[b2];
        boff = r;
    }
    __syncthreads();
    int i = blockIdx.x * 1024 + threadIdx.x;
    if (i < n) row_ptr[i] += boff;
    if (i == n) row_ptr[n] = e;
}

// atomic-free CSR column fill
__global__ void scatter_kernel(const int* __restrict__ src, const int* __restrict__ dst,
                               const int* __restrict__ row_ptr, const int* __restrict__ rank,
                               int* __restrict__ col_idx, int e) {
    int i = blockIdx.x * blockDim.x + threadIdx.x;
    if (i < e) col_idx[row_ptr[dst[i]] + rank[i]] = src[i];
}

// embedding gather (bf16) + weight transpose/convert, one kernel
__global__ void embed_prep(const int* __restrict__ node_ids, const float* __restrict__ emb,
                           unsigned short* __restrict__ x, int n32,
                           const float* __restrict__ Ws, const float* __restrict__ Rws,
                           unsigned short* __restrict__ Wt, unsigned short* __restrict__ Rwt,
                           int wtotal) {
    int gid = blockIdx.x * blockDim.x + threadIdx.x;
    if (gid < n32) {
        int v = gid >> 5, c4 = gid & 31;
        int id = node_ids[v];
        float4 e = *(const float4*)&emb[id * 128 + c4 * 4];
        ushort4 o;
        o.x = f2bf(e.x); o.y = f2bf(e.y); o.z = f2bf(e.z); o.w = f2bf(e.w);
        *(ushort4*)&x[(size_t)v * 128 + c4 * 4] = o;
    }
    if (gid < wtotal) {
        int l = gid >> 14, r = (gid >> 7) & 127, k = gid & 127;
        int sidx = l * 16384 + k * 128 + r;
        Wt[gid]  = f2bf(Ws[sidx]);
        Rwt[gid] = f2bf(Rws[sidx]);
    }
}

// ---------------- fused per-layer kernel ----------------
// Phase 1 (gather): 4 thr/node x 64 nodes; each thread owns 32 cols; edges processed
//   in batches of 4 -> 16 independent uint4 loads in flight per lane.
// Phase 2: dual GEMM via MFMA 16x16x32 bf16 (conv A from LDS, residual A from global x).
// Epilogue: bias+relu+add -> h, BN sum/sumsq -> NBANK-banked global stats.
#define GM 64
#define APAD 136   // 128+8 shorts: 272 B row stride (bank stride 4 -> 2-way, free)
__global__ __launch_bounds__(256, 3) void fused_layer_kernel(
    const unsigned short* __restrict__ x,
    const int* __restrict__ row_ptr, const int* __restrict__ col_idx,
    const float* __restrict__ out_norm, const float* __restrict__ in_norm,
    const unsigned short* __restrict__ Wt, const unsigned short* __restrict__ Rwt,
    const float* __restrict__ bvec, const float* __restrict__ Rbvec,
    float* __restrict__ h, float* __restrict__ stats, int nrows) {
    __shared__ unsigned short As[GM * APAD];
    __shared__ float bsum[128], bss[128];
    int tid = threadIdx.x;
    int m0 = blockIdx.x * GM;
    if (tid < 128) { bsum[tid] = 0.f; bss[tid] = 0.f; }

    // ---- phase 1: gather ----
    {
        int node = tid >> 2;
        int part = tid & 3;
        int gnode = m0 + node;
        float acc[32];
        #pragma unroll
        for (int j = 0; j < 32; j++) acc[j] = 0.f;
        if (gnode < nrows) {
            int beg = row_ptr[gnode], end = row_ptr[gnode + 1];
            const unsigned short* xb = x + part * 32;
            for (int e = beg; e < end; e += 4) {
                int ne = end - e;
                int u0 = col_idx[e];
                int u1 = col_idx[ne > 1 ? e + 1 : e];
                int u2 = col_idx[ne > 2 ? e + 2 : e];
                int u3 = col_idx[ne > 3 ? e + 3 : e];
                float n0 = out_norm[u0];
                float n1 = ne > 1 ? out_norm[u1] : 0.f;
                float n2 = ne > 2 ? out_norm[u2] : 0.f;
                float n3 = ne > 3 ? out_norm[u3] : 0.f;
                const uint4* p0 = (const uint4*)(xb + (size_t)u0 * 128);
                const uint4* p1 = (const uint4*)(xb + (size_t)u1 * 128);
                const uint4* p2 = (const uint4*)(xb + (size_t)u2 * 128);
                const uint4* p3 = (const uint4*)(xb + (size_t)u3 * 128);
                uint4 q[4][4];
                #pragma unroll
                for (int c = 0; c < 4; c++) { q[0][c] = p0[c]; }
                #pragma unroll
                for (int c = 0; c < 4; c++) { q[1][c] = p1[c]; }
                #pragma unroll
                for (int c = 0; c < 4; c++) { q[2][c] = p2[c]; }
                #pragma unroll
                for (int c = 0; c < 4; c++) { q[3][c] = p3[c]; }
                float nn[4] = {n0, n1, n2, n3};
                #pragma unroll
                for (int r = 0; r < 4; r++) {
                    const unsigned int* w = (const unsigned int*)&q[r][0];
                    float nr = nn[r];
                    #pragma unroll
                    for (int t = 0; t < 16; t++) {
                        acc[2 * t]     += nr * bf2f((unsigned short)w[t]);
                        acc[2 * t + 1] += nr * bf2f((unsigned short)(w[t] >> 16));
                    }
                }
            }
            float inv = in_norm[gnode];
            #pragma unroll
            for (int j = 0; j < 32; j++) acc[j] *= inv;
        }
        unsigned short* dstp = &As[node * APAD + part * 32];
        #pragma unroll
        for (int j = 0; j < 4; j++) {
            uint4 pk;
            pk.x = (unsigned int)f2bf(acc[8 * j + 0]) | ((unsigned int)f2bf(acc[8 * j + 1]) << 16);
            pk.y = (unsigned int)f2bf(acc[8 * j + 2]) | ((unsigned int)f2bf(acc[8 * j + 3]) << 16);
            pk.z = (unsigned int)f2bf(acc[8 * j + 4]) | ((unsigned int)f2bf(acc[8 * j + 5]) << 16);
            pk.w = (unsigned int)f2bf(acc[8 * j + 6]) | ((unsigned int)f2bf(acc[8 * j + 7]) << 16);
            *(uint4*)&dstp[8 * j] = pk;
        }
    }
    __syncthreads();

    // ---- phase 2: dual GEMM via MFMA 16x16x32 bf16 ----
    int wave = tid >> 6;
    int lane = tid & 63;
    int m = lane & 15;
    int quad = lane >> 4;
    int r0 = wave * 16;
    int grx = m0 + r0 + m;
    if (grx >= nrows) grx = nrows - 1;   // clamp; OOB rows discarded in epilogue

    f32x4 accA[8], accX[8];
    #pragma unroll
    for (int t = 0; t < 8; t++) { accA[t] = (f32x4){0,0,0,0}; accX[t] = (f32x4){0,0,0,0}; }

    #pragma unroll
    for (int kc = 0; kc < 4; kc++) {
        int koff = kc * 32 + quad * 8;
        bf16x8 aA = *(const bf16x8*)&As[(r0 + m) * APAD + koff];
        bf16x8 aX = *(const bf16x8*)&x[(size_t)grx * 128 + koff];
        #pragma unroll
        for (int nt = 0; nt < 8; nt++) {
            int nrow = nt * 16 + m;
            bf16x8 bW = *(const bf16x8*)&Wt[(size_t)nrow * 128 + koff];
            bf16x8 bR = *(const bf16x8*)&Rwt[(size_t)nrow * 128 + koff];
            accA[nt] = __builtin_amdgcn_mfma_f32_16x16x32_bf16(aA, bW, accA[nt], 0, 0, 0);
            accX[nt] = __builtin_amdgcn_mfma_f32_16x16x32_bf16(aX, bR, accX[nt], 0, 0, 0);
        }
    }

    // ---- epilogue ----
    #pragma unroll
    for (int nt = 0; nt < 8; nt++) {
        int col = nt * 16 + m;
        float bW = bvec[col], bR = Rbvec[col];
        float cs = 0.f, cq = 0.f;
        #pragma unroll
        for (int reg = 0; reg < 4; reg++) {
            int gr = m0 + r0 + quad * 4 + reg;
            float hA = accA[nt][reg] + bW; hA = hA > 0.f ? hA : 0.f;
            float hX = accX[nt][reg] + bR; hX = hX > 0.f ? hX : 0.f;
            float v = hA + hX;
            if (gr < nrows) {
                h[(size_t)gr * 128 + col] = v;
            } else {
                v = 0.f;
            }
            cs += v; cq += v * v;
        }
        cs += __shfl_xor(cs, 16); cs += __shfl_xor(cs, 32);
        cq += __shfl_xor(cq, 16); cq += __shfl_xor(cq, 32);
        if (lane < 16) {
            atomicAdd(&bsum[col], cs);
            atomicAdd(&bss[col], cq);
        }
    }
    __syncthreads();
    if (tid < 128) {
        float* sb = stats + (size_t)(blockIdx.x & (NBANK - 1)) * 256;
        atomicAdd(&sb[tid], bsum[tid]);
        atomicAdd(&sb[tid + 128], bss[tid]);
    }
}

// ---------------- BN apply (finalize folded in) ----------------

// intermediate layers: write bf16 x for the next layer
__global__ void norm_apply_bf16(const float* __restrict__ h, const float* __restrict__ stats,
                                const float* __restrict__ gamma, const float* __restrict__ beta,
                                unsigned short* __restrict__ dstp, int total4, float n) {
    __shared__ float ssc[128], ssh[128];
    int t = threadIdx.x;
    if (t < 128) {
        float s = 0.f, sq = 0.f;
        #pragma unroll
        for (int b2 = 0; b2 < NBANK; b2++) {
            s  += stats[b2 * 256 + t];
            sq += stats[b2 * 256 + t + 128];
        }
        float mu = s / n;
        float var = sq / n - mu * mu;
        float rstd = rsqrtf(var + 1e-5f);
        float sc = gamma[t] * rstd;
        ssc[t] = sc;
        ssh[t] = beta[t] - sc * mu;
    }
    __syncthreads();
    int gid = blockIdx.x * blockDim.x + t;
    if (gid >= total4) return;
    int c4 = gid & 31;
    float4 sc = *(const float4*)&ssc[c4 * 4];
    float4 sh = *(const float4*)&ssh[c4 * 4];
    float4 v = ((const float4*)h)[gid];
    ushort4 o;
    o.x = f2bf(sc.x * v.x + sh.x);
    o.y = f2bf(sc.y * v.y + sh.y);
    o.z = f2bf(sc.z * v.z + sh.z);
    o.w = f2bf(sc.w * v.w + sh.w);
    ((ushort4*)dstp)[gid] = o;
}

// final layer: fp32 out
__global__ void norm_apply_f32(const float* __restrict__ h, const float* __restrict__ stats,
                               const float* __restrict__ gamma, const float* __restrict__ beta,
                               float* __restrict__ dstp, int total4, float n) {
    __shared__ float ssc[128], ssh[128];
    int t = threadIdx.x;
    if (t < 128) {
        float s = 0.f, sq = 0.f;
        #pragma unroll
        for (int b2 = 0; b2 < NBANK; b2++) {
            s  += stats[b2 * 256 + t];
            sq += stats[b2 * 256 + t + 128];
        }
        float mu = s / n;
        float var = sq / n - mu * mu;
        float rstd = rsqrtf(var + 1e-5f);
        float sc = gamma[t] * rstd;
        ssc[t] = sc;
        ssh[t] = beta[t] - sc * mu;
    }
    __syncthreads();
    int gid = blockIdx.x * blockDim.x + t;
    if (gid >= total4) return;
    int c4 = gid & 31;
    float4 sc = *(const float4*)&ssc[c4 * 4];
    float4 sh = *(const float4*)&ssh[c4 * 4];
    float4 v = ((const float4*)h)[gid];
    float4 o;
    o.x = sc.x * v.x + sh.x;
    o.y = sc.y * v.y + sh.y;
    o.z = sc.z * v.z + sh.z;
    o.w = sc.w * v.w + sh.w;
    ((float4*)dstp)[gid] = o;
}

// ---------------- launch ----------------

extern "C" void kernel_launch(void* const* d_in, const int* in_sizes, int n_in,
                              void* d_out, int out_size, void* d_ws, size_t ws_size,
                              hipStream_t stream) {
    const int*   node_ids = (const int*)d_in[0];
    const int*   src      = (const int*)d_in[1];
    const int*   dst      = (const int*)d_in[2];
    const float* emb      = (const float*)d_in[3];
    const float* Ws       = (const float*)d_in[4];
    const float* bs       = (const float*)d_in[5];
    const float* Rws      = (const float*)d_in[6];
    const float* Rbs      = (const float*)d_in[7];
    const float* gammas   = (const float*)d_in[8];
    const float* betas    = (const float*)d_in[9];

    const int N = in_sizes[0];
    const int E = in_sizes[1];
    const int D = 128;
    const int L = in_sizes[4] / (D * D);

    size_t off = 0;
    auto alloc = [&](size_t bytes) -> void* {
        void* p = (char*)d_ws + off;
        off += (bytes + 255) & ~(size_t)255;
        return p;
    };
    int*   degs     = (int*)alloc((size_t)2 * N * 4);   // deg_src | deg_dst (one memset)
    int*   deg_src  = degs;
    int*   deg_dst  = degs + N;
    int*   rank     = (int*)alloc((size_t)E * 4);
    float* out_norm = (float*)alloc((size_t)N * 4);
    float* in_norm  = (float*)alloc((size_t)N * 4);
    int*   row_ptr  = (int*)alloc((size_t)(N + 1) * 4);
    int*   bsumg    = (int*)alloc(64 * 4);
    int*   col_idx  = (int*)alloc((size_t)E * 4);
    float* stats    = (float*)alloc((size_t)L * NBANK * 256 * 4);
    unsigned short* Wt  = (unsigned short*)alloc((size_t)L * D * D * 2);
    unsigned short* Rwt = (unsigned short*)alloc((size_t)L * D * D * 2);
    unsigned short* x   = (unsigned short*)alloc((size_t)N * D * 2);
    float* h = (float*)d_out;  // fp32 h scratch == output buffer

    hipMemsetAsync(degs, 0, (size_t)2 * N * 4, stream);
    hipMemsetAsync(stats, 0, (size_t)L * NBANK * 256 * 4, stream);

    degree_kernel<<<(E + TPB - 1) / TPB, TPB, 0, stream>>>(src, dst, deg_src, deg_dst, rank, E);
    int nb = (N + 1023) / 1024;
    scan1_norm<<<nb, 1024, 0, stream>>>(deg_src, deg_dst, out_norm, in_norm, row_ptr, bsumg, N);
    scan_apply<<<nb, 1024, 0, stream>>>(bsumg, row_ptr, N, E);
    scatter_kernel<<<(E + TPB - 1) / TPB, TPB, 0, stream>>>(src, dst, row_ptr, rank, col_idx, E);
    int n32 = N * 32, wtotal = L * D * D;
    int epg = ((n32 > wtotal ? n32 : wtotal) + TPB - 1) / TPB;
    embed_prep<<<epg, TPB, 0, stream>>>(node_ids, emb, x, n32, Ws, Rws, Wt, Rwt, wtotal);

    int gblocks = (N + GM - 1) / GM;
    for (int l = 0; l < L; l++) {
        const unsigned short* Wtl  = Wt  + (size_t)l * D * D;
        const unsigned short* Rwtl = Rwt + (size_t)l * D * D;
        const float* b   = bs  + (size_t)l * D;
        const float* Rb  = Rbs + (size_t)l * D;
        const float* gm  = gammas + (size_t)l * D;
        const float* bt  = betas  + (size_t)l * D;
        float* st = stats + (size_t)l * NBANK * 256;

        fused_layer_kernel<<<gblocks, TPB, 0, stream>>>(
            x, row_ptr, col_idx, out_norm, in_norm, Wtl, Rwtl, b, Rb, h, st, N);
        if (l < L - 1) {
            norm_apply_bf16<<<(N * 32 + TPB - 1) / TPB, TPB, 0, stream>>>(
                h, st, gm, bt, x, N * 32, (float)N);
        } else {
            norm_apply_f32<<<(N * 32 + TPB - 1) / TPB, TPB, 0, stream>>>(
                h, st, gm, bt, (float*)d_out, N * 32, (float)N);
        }
    }
}

// Round 5
// 313.540 us; speedup vs baseline: 1.9540x; 1.2178x over previous
//
#include <hip/hip_runtime.h>
#include <hip/hip_bf16.h>

// GCN node encoder: 3 layers GraphConv(norm=both) + residual linear + ReLU + BatchNorm.
// N=50000, E=500000, D=128, L=3.
// Round 5: GM=16 fused kernel. 16 thr/node x 8 cols; 8-edge batches (8 independent
// 16-B row loads in flight per lane, register-audited ~70 VGPR); (src,norm) packed
// int2 edge descriptors (no dependent norm lookup); 3125 blocks (~24 waves/CU).

#define TPB 256
#define NBANK 8   // stat accumulator banks
#define GM 16
#define APAD 136  // 128+8 shorts: 272 B row stride

typedef __attribute__((ext_vector_type(8))) short bf16x8;   // 8 bf16 = 4 VGPRs
typedef __attribute__((ext_vector_type(4))) float f32x4;

__device__ inline unsigned short f2bf(float f) {
    unsigned int u = __builtin_bit_cast(unsigned int, f);
    u += 0x7fff + ((u >> 16) & 1);          // RNE
    return (unsigned short)(u >> 16);
}
__device__ inline float bf2f(unsigned short b) {
    unsigned int u = ((unsigned int)b) << 16;
    return __builtin_bit_cast(float, u);
}

// ---------------- setup kernels ----------------

// degrees + per-edge rank (old value of dst-degree counter)
__global__ void degree_kernel(const int* __restrict__ src, const int* __restrict__ dst,
                              int* __restrict__ deg_src, int* __restrict__ deg_dst,
                              int* __restrict__ rank, int e) {
    int i = blockIdx.x * blockDim.x + threadIdx.x;
    if (i < e) {
        atomicAdd(&deg_src[src[i]], 1);
        rank[i] = atomicAdd(&deg_dst[dst[i]], 1);
    }
}

// block-local exclusive scan of deg_dst into row_ptr, block sums to bsum; also norms
__global__ void scan1_norm(const int* __restrict__ deg_src, const int* __restrict__ deg_dst,
                           float* __restrict__ out_norm, float* __restrict__ in_norm,
                           int* __restrict__ row_ptr, int* __restrict__ bsum, int n) {
    __shared__ int tmp[1024];
    int t = threadIdx.x;
    int i = blockIdx.x * 1024 + t;
    int v = (i < n) ? deg_dst[i] : 0;
    tmp[t] = v;
    __syncthreads();
    for (int off = 1; off < 1024; off <<= 1) {
        int add = (t >= off) ? tmp[t - off] : 0;
        __syncthreads();
        tmp[t] += add;
        __syncthreads();
    }
    if (i < n) {
        row_ptr[i] = tmp[t] - v;
        int dsv = deg_src[i];
        out_norm[i] = dsv > 0 ? rsqrtf((float)dsv) : 0.f;
        in_norm[i]  = v   > 0 ? rsqrtf((float)v)   : 0.f;
    }
    if (t == 1023) bsum[blockIdx.x] = tmp[1023];
}

// add block offset in place; set row_ptr[n]=e
__global__ void scan_apply(const int* __restrict__ bsum, int* __restrict__ row_ptr,
                           int n, int e) {
    __shared__ int boff;
    if (threadIdx.x == 0) {
        int r = 0;
        for (int b2 = 0; b2 < blockIdx.x; b2++) r += bsum[b2];
        boff = r;
    }
    __syncthreads();
    int i = blockIdx.x * 1024 + threadIdx.x;
    if (i < n) row_ptr[i] += boff;
    if (i == n) row_ptr[n] = e;
}

// atomic-free CSR fill with packed (src, out_norm[src]) descriptors
__global__ void scatter_kernel(const int* __restrict__ src, const int* __restrict__ dst,
                               const int* __restrict__ row_ptr, const int* __restrict__ rank,
                               const float* __restrict__ out_norm,
                               int2* __restrict__ col_un, int e) {
    int i = blockIdx.x * blockDim.x + threadIdx.x;
    if (i < e) {
        int s = src[i];
        int2 v;
        v.x = s;
        v.y = __float_as_int(out_norm[s]);
        col_un[row_ptr[dst[i]] + rank[i]] = v;
    }
}

// embedding gather (bf16) + weight transpose/convert, one kernel
__global__ void embed_prep(const int* __restrict__ node_ids, const float* __restrict__ emb,
                           unsigned short* __restrict__ x, int n32,
                           const float* __restrict__ Ws, const float* __restrict__ Rws,
                           unsigned short* __restrict__ Wt, unsigned short* __restrict__ Rwt,
                           int wtotal) {
    int gid = blockIdx.x * blockDim.x + threadIdx.x;
    if (gid < n32) {
        int v = gid >> 5, c4 = gid & 31;
        int id = node_ids[v];
        float4 e = *(const float4*)&emb[id * 128 + c4 * 4];
        ushort4 o;
        o.x = f2bf(e.x); o.y = f2bf(e.y); o.z = f2bf(e.z); o.w = f2bf(e.w);
        *(ushort4*)&x[(size_t)v * 128 + c4 * 4] = o;
    }
    if (gid < wtotal) {
        int l = gid >> 14, r = (gid >> 7) & 127, k = gid & 127;
        int sidx = l * 16384 + k * 128 + r;
        Wt[gid]  = f2bf(Ws[sidx]);
        Rwt[gid] = f2bf(Rws[sidx]);
    }
}

// ---------------- fused per-layer kernel ----------------
// Gather: 16 thr/node x 16 nodes; thread owns 8 cols (one uint4 per edge row-chunk).
//   8-edge batches: 8 int2 descriptor loads + 8 uint4 row loads, all independent.
//   Also stages the block's own x rows into Xs for the residual GEMM.
// MFMA: 4 waves x 2 col-tiles each; conv A from As, residual A from Xs, B from Wt/Rwt.
// Epilogue: bias+relu+add -> h (fp32), BN sum/sumsq -> NBANK-banked global stats.
__global__ __launch_bounds__(256, 6) void fused_layer_kernel(
    const unsigned short* __restrict__ x,
    const int* __restrict__ row_ptr, const int2* __restrict__ col_un,
    const float* __restrict__ in_norm,
    const unsigned short* __restrict__ Wt, const unsigned short* __restrict__ Rwt,
    const float* __restrict__ bvec, const float* __restrict__ Rbvec,
    float* __restrict__ h, float* __restrict__ stats, int nrows) {
    __shared__ unsigned short As[GM * APAD];
    __shared__ unsigned short Xs[GM * APAD];
    __shared__ float bsum[128], bss[128];
    int tid = threadIdx.x;
    int m0 = blockIdx.x * GM;
    if (tid < 128) { bsum[tid] = 0.f; bss[tid] = 0.f; }

    // ---- gather ----
    {
        int node = tid >> 4;
        int part = tid & 15;
        int gnode = m0 + node;
        if (gnode >= nrows) gnode = nrows - 1;   // N%GM==0 in practice
        // stage own x row chunk for residual GEMM
        uint4 xv = *(const uint4*)&x[(size_t)gnode * 128 + part * 8];
        *(uint4*)&Xs[node * APAD + part * 8] = xv;
        float inv = in_norm[gnode];
        int beg = row_ptr[gnode], end = row_ptr[gnode + 1];
        float acc[8];
        #pragma unroll
        for (int j = 0; j < 8; j++) acc[j] = 0.f;
        const unsigned short* xb = x + part * 8;
        for (int e = beg; e < end; e += 8) {
            int rem = end - e;
            int2 ed[8];
            #pragma unroll
            for (int j = 0; j < 8; j++) ed[j] = col_un[e + j];   // padded tail is zeroed
            uint4 q[8];
            #pragma unroll
            for (int j = 0; j < 8; j++)
                q[j] = *(const uint4*)(xb + (size_t)(unsigned)ed[j].x * 128);
            #pragma unroll
            for (int j = 0; j < 8; j++) {
                float nn = (j < rem) ? __int_as_float(ed[j].y) : 0.f;
                const unsigned int* w = (const unsigned int*)&q[j];
                #pragma unroll
                for (int t = 0; t < 4; t++) {
                    acc[2 * t]     += nn * bf2f((unsigned short)w[t]);
                    acc[2 * t + 1] += nn * bf2f((unsigned short)(w[t] >> 16));
                }
            }
        }
        #pragma unroll
        for (int j = 0; j < 8; j++) acc[j] *= inv;
        uint4 pk;
        pk.x = (unsigned int)f2bf(acc[0]) | ((unsigned int)f2bf(acc[1]) << 16);
        pk.y = (unsigned int)f2bf(acc[2]) | ((unsigned int)f2bf(acc[3]) << 16);
        pk.z = (unsigned int)f2bf(acc[4]) | ((unsigned int)f2bf(acc[5]) << 16);
        pk.w = (unsigned int)f2bf(acc[6]) | ((unsigned int)f2bf(acc[7]) << 16);
        *(uint4*)&As[node * APAD + part * 8] = pk;
    }
    __syncthreads();

    // ---- dual GEMM via MFMA 16x16x32 bf16 ----
    int wave = tid >> 6;
    int lane = tid & 63;
    int m = lane & 15;
    int quad = lane >> 4;

    f32x4 accA[2], accX[2];
    #pragma unroll
    for (int t = 0; t < 2; t++) { accA[t] = (f32x4){0,0,0,0}; accX[t] = (f32x4){0,0,0,0}; }

    #pragma unroll
    for (int kc = 0; kc < 4; kc++) {
        int koff = kc * 32 + quad * 8;
        bf16x8 aA = *(const bf16x8*)&As[m * APAD + koff];
        bf16x8 aX = *(const bf16x8*)&Xs[m * APAD + koff];
        #pragma unroll
        for (int t = 0; t < 2; t++) {
            int nrow = (wave * 2 + t) * 16 + m;
            bf16x8 bW = *(const bf16x8*)&Wt[(size_t)nrow * 128 + koff];
            bf16x8 bR = *(const bf16x8*)&Rwt[(size_t)nrow * 128 + koff];
            accA[t] = __builtin_amdgcn_mfma_f32_16x16x32_bf16(aA, bW, accA[t], 0, 0, 0);
            accX[t] = __builtin_amdgcn_mfma_f32_16x16x32_bf16(aX, bR, accX[t], 0, 0, 0);
        }
    }

    // ---- epilogue ----
    #pragma unroll
    for (int t = 0; t < 2; t++) {
        int col = (wave * 2 + t) * 16 + m;
        float bW = bvec[col], bR = Rbvec[col];
        float cs = 0.f, cq = 0.f;
        #pragma unroll
        for (int reg = 0; reg < 4; reg++) {
            int gr = m0 + quad * 4 + reg;
            float hA = accA[t][reg] + bW; hA = hA > 0.f ? hA : 0.f;
            float hX = accX[t][reg] + bR; hX = hX > 0.f ? hX : 0.f;
            float v = hA + hX;
            if (gr < nrows) {
                h[(size_t)gr * 128 + col] = v;
            } else {
                v = 0.f;
            }
            cs += v; cq += v * v;
        }
        cs += __shfl_xor(cs, 16); cs += __shfl_xor(cs, 32);
        cq += __shfl_xor(cq, 16); cq += __shfl_xor(cq, 32);
        if (lane < 16) {
            atomicAdd(&bsum[col], cs);
            atomicAdd(&bss[col], cq);
        }
    }
    __syncthreads();
    if (tid < 128) {
        float* sb = stats + (size_t)(blockIdx.x & (NBANK - 1)) * 256;
        atomicAdd(&sb[tid], bsum[tid]);
        atomicAdd(&sb[tid + 128], bss[tid]);
    }
}

// ---------------- BN apply (finalize folded in) ----------------

__global__ void norm_apply_bf16(const float* __restrict__ h, const float* __restrict__ stats,
                                const float* __restrict__ gamma, const float* __restrict__ beta,
                                unsigned short* __restrict__ dstp, int total4, float n) {
    __shared__ float ssc[128], ssh[128];
    int t = threadIdx.x;
    if (t < 128) {
        float s = 0.f, sq = 0.f;
        #pragma unroll
        for (int b2 = 0; b2 < NBANK; b2++) {
            s  += stats[b2 * 256 + t];
            sq += stats[b2 * 256 + t + 128];
        }
        float mu = s / n;
        float var = sq / n - mu * mu;
        float rstd = rsqrtf(var + 1e-5f);
        float sc = gamma[t] * rstd;
        ssc[t] = sc;
        ssh[t] = beta[t] - sc * mu;
    }
    __syncthreads();
    int gid = blockIdx.x * blockDim.x + t;
    if (gid >= total4) return;
    int c4 = gid & 31;
    float4 sc = *(const float4*)&ssc[c4 * 4];
    float4 sh = *(const float4*)&ssh[c4 * 4];
    float4 v = ((const float4*)h)[gid];
    ushort4 o;
    o.x = f2bf(sc.x * v.x + sh.x);
    o.y = f2bf(sc.y * v.y + sh.y);
    o.z = f2bf(sc.z * v.z + sh.z);
    o.w = f2bf(sc.w * v.w + sh.w);
    ((ushort4*)dstp)[gid] = o;
}

__global__ void norm_apply_f32(const float* __restrict__ h, const float* __restrict__ stats,
                               const float* __restrict__ gamma, const float* __restrict__ beta,
                               float* __restrict__ dstp, int total4, float n) {
    __shared__ float ssc[128], ssh[128];
    int t = threadIdx.x;
    if (t < 128) {
        float s = 0.f, sq = 0.f;
        #pragma unroll
        for (int b2 = 0; b2 < NBANK; b2++) {
            s  += stats[b2 * 256 + t];
            sq += stats[b2 * 256 + t + 128];
        }
        float mu = s / n;
        float var = sq / n - mu * mu;
        float rstd = rsqrtf(var + 1e-5f);
        float sc = gamma[t] * rstd;
        ssc[t] = sc;
        ssh[t] = beta[t] - sc * mu;
    }
    __syncthreads();
    int gid = blockIdx.x * blockDim.x + t;
    if (gid >= total4) return;
    int c4 = gid & 31;
    float4 sc = *(const float4*)&ssc[c4 * 4];
    float4 sh = *(const float4*)&ssh[c4 * 4];
    float4 v = ((const float4*)h)[gid];
    float4 o;
    o.x = sc.x * v.x + sh.x;
    o.y = sc.y * v.y + sh.y;
    o.z = sc.z * v.z + sh.z;
    o.w = sc.w * v.w + sh.w;
    ((float4*)dstp)[gid] = o;
}

// ---------------- launch ----------------

extern "C" void kernel_launch(void* const* d_in, const int* in_sizes, int n_in,
                              void* d_out, int out_size, void* d_ws, size_t ws_size,
                              hipStream_t stream) {
    const int*   node_ids = (const int*)d_in[0];
    const int*   src      = (const int*)d_in[1];
    const int*   dst      = (const int*)d_in[2];
    const float* emb      = (const float*)d_in[3];
    const float* Ws       = (const float*)d_in[4];
    const float* bs       = (const float*)d_in[5];
    const float* Rws      = (const float*)d_in[6];
    const float* Rbs      = (const float*)d_in[7];
    const float* gammas   = (const float*)d_in[8];
    const float* betas    = (const float*)d_in[9];

    const int N = in_sizes[0];
    const int E = in_sizes[1];
    const int D = 128;
    const int L = in_sizes[4] / (D * D);

    size_t off = 0;
    auto alloc = [&](size_t bytes) -> void* {
        void* p = (char*)d_ws + off;
        off += (bytes + 255) & ~(size_t)255;
        return p;
    };
    int*   degs     = (int*)alloc((size_t)2 * N * 4);   // deg_src | deg_dst
    int*   deg_src  = degs;
    int*   deg_dst  = degs + N;
    int*   rank     = (int*)alloc((size_t)E * 4);
    float* out_norm = (float*)alloc((size_t)N * 4);
    float* in_norm  = (float*)alloc((size_t)N * 4);
    int*   row_ptr  = (int*)alloc((size_t)(N + 1) * 4);
    int*   bsumg    = (int*)alloc(64 * 4);
    int2*  col_un   = (int2*)alloc(((size_t)E + 8) * 8);
    float* stats    = (float*)alloc((size_t)L * NBANK * 256 * 4);
    unsigned short* Wt  = (unsigned short*)alloc((size_t)L * D * D * 2);
    unsigned short* Rwt = (unsigned short*)alloc((size_t)L * D * D * 2);
    unsigned short* x   = (unsigned short*)alloc((size_t)N * D * 2);
    float* h = (float*)d_out;  // fp32 h scratch == output buffer

    hipMemsetAsync(degs, 0, (size_t)2 * N * 4, stream);
    hipMemsetAsync(stats, 0, (size_t)L * NBANK * 256 * 4, stream);
    hipMemsetAsync(col_un + E, 0, 8 * sizeof(int2), stream);   // pad for 8-edge batches

    degree_kernel<<<(E + TPB - 1) / TPB, TPB, 0, stream>>>(src, dst, deg_src, deg_dst, rank, E);
    int nb = (N + 1023) / 1024;
    scan1_norm<<<nb, 1024, 0, stream>>>(deg_src, deg_dst, out_norm, in_norm, row_ptr, bsumg, N);
    scan_apply<<<nb, 1024, 0, stream>>>(bsumg, row_ptr, N, E);
    scatter_kernel<<<(E + TPB - 1) / TPB, TPB, 0, stream>>>(src, dst, row_ptr, rank,
                                                            out_norm, col_un, E);
    int n32 = N * 32, wtotal = L * D * D;
    int epg = ((n32 > wtotal ? n32 : wtotal) + TPB - 1) / TPB;
    embed_prep<<<epg, TPB, 0, stream>>>(node_ids, emb, x, n32, Ws, Rws, Wt, Rwt, wtotal);

    int gblocks = (N + GM - 1) / GM;
    for (int l = 0; l < L; l++) {
        const unsigned short* Wtl  = Wt  + (size_t)l * D * D;
        const unsigned short* Rwtl = Rwt + (size_t)l * D * D;
        const float* b   = bs  + (size_t)l * D;
        const float* Rb  = Rbs + (size_t)l * D;
        const float* gm  = gammas + (size_t)l * D;
        const float* bt  = betas  + (size_t)l * D;
        float* st = stats + (size_t)l * NBANK * 256;

        fused_layer_kernel<<<gblocks, TPB, 0, stream>>>(
            x, row_ptr, col_un, in_norm, Wtl, Rwtl, b, Rb, h, st, N);
        if (l < L - 1) {
            norm_apply_bf16<<<(N * 32 + TPB - 1) / TPB, TPB, 0, stream>>>(
                h, st, gm, bt, x, N * 32, (float)N);
        } else {
            norm_apply_f32<<<(N * 32 + TPB - 1) / TPB, TPB, 0, stream>>>(
                h, st, gm, bt, (float*)d_out, N * 32, (float)N);
        }
    }
}